// Round 4
// baseline (907.363 us; speedup 1.0000x reference)
//
#include <hip/hip_runtime.h>

typedef unsigned short u16;
typedef unsigned int u32;
typedef __attribute__((ext_vector_type(8))) short bf16x8;
typedef __attribute__((ext_vector_type(4))) float f32x4;

#define BB 4096
#define NS 26
#define DNS 13
#define DD 16
#define VV 100000
#define FF 128
#define NF 39
#define BD 65536
#define DIN_PAD 448

__device__ __forceinline__ float bf2f(u16 x) {
    union { u32 u; float f; } v; v.u = ((u32)x) << 16; return v.f;
}
__device__ __forceinline__ u16 f2bf(float f) {
    union { float f; u32 u; } v; v.f = f;
    u32 u = v.u;
    u32 r = (u + 0x7fffu + ((u >> 16) & 1u)) >> 16;
    return (u16)r;
}

// ---------------- prep kernels (f32 in -> bf16 workspace) ----------------

__global__ void prep_x0_k(const float* __restrict__ emb_W, const int* __restrict__ disc,
                          const float* __restrict__ dense_x, const float* __restrict__ dense_proj,
                          u16* __restrict__ x0) {
    int e = blockIdx.x * 256 + threadIdx.x;   // BD*64
    int c = e & 63;
    int j = e >> 6;
    int b = j >> 4, d = j & 15;
    float v = 0.f;
    if (c < NS) {
        int ix = disc[b * NS + c];
        v = emb_W[((size_t)c * VV + ix) * DD + d];
    } else if (c < NF) {
        int q = c - NS;
        v = dense_x[b * DNS + q] * dense_proj[q * DD + d];
    }
    x0[e] = f2bf(v);
}

__global__ void prep_h0_k(const float* __restrict__ emb_W, const int* __restrict__ disc,
                          const float* __restrict__ dense_x, u16* __restrict__ h0) {
    int e = blockIdx.x * 256 + threadIdx.x;   // B*448
    int col = e % DIN_PAD;
    int b = e / DIN_PAD;
    float v = 0.f;
    if (col < NS * DD) {
        int n = col >> 4, d = col & 15;
        int ix = disc[b * NS + n];
        v = emb_W[((size_t)n * VV + ix) * DD + d];
    } else if (col < NS * DD + DNS) {
        v = dense_x[b * DNS + col - NS * DD];
    }
    h0[e] = f2bf(v);
}

// tiled transpose: dst[n*Kpad + k] = src[k*Nn + n], zero-pad k in [K, Kpad)
__global__ void transpose_pad_k(const float* __restrict__ src, u16* __restrict__ dst,
                                int K, int Nn, int Kpad) {
    __shared__ u16 t[64][72];
    const int kb = blockIdx.x * 64, nb = blockIdx.y * 64;
    for (int i = threadIdx.x; i < 64 * 64; i += 256) {
        int kk = i >> 6, nn = i & 63;
        int k = kb + kk, n = nb + nn;
        float v = (k < K && n < Nn) ? src[(size_t)k * Nn + n] : 0.f;
        t[nn][kk] = f2bf(v);
    }
    __syncthreads();
    for (int i = threadIdx.x; i < 64 * 64; i += 256) {
        int nn = i >> 6, kk = i & 63;
        int n = nb + nn, k = kb + kk;
        if (n < Nn && k < Kpad) dst[(size_t)n * Kpad + k] = t[nn][kk];
    }
}

// cin weight rearrange: dst[n][f][c(pad)] = W[f,c,n]  (src is [f][C][NF], contiguous n)
// coalesced read of 256 consecutive (f,c)-pairs' n-runs, LDS transpose, coalesced write.
// pads c in [C,Cpad) are pre-zeroed by hipMemsetAsync.
__global__ void cinw_k(const float* __restrict__ src, u16* __restrict__ dst, int C, int Cpad) {
    __shared__ u16 tile[256][40];
    const int fc0 = blockIdx.x * 256;
    const int total = 128 * C;
    for (int i = threadIdx.x; i < 256 * NF; i += 256) {
        int e = fc0 * NF + i;
        if (e < total * NF) {
            int fcl = i / NF, n = i % NF;
            tile[fcl][n] = f2bf(src[e]);
        }
    }
    __syncthreads();
    for (int i = threadIdx.x; i < 256 * NF; i += 256) {
        int n = i >> 8, fcl = i & 255;
        int fc = fc0 + fcl;
        if (fc < total) {
            int f = fc / C, c = fc % C;
            dst[(size_t)n * 128 * Cpad + f * Cpad + c] = tile[fcl][n];
        }
    }
}

// ---------------- DNN GEMM: C = relu(bn(A@W + bias)) ----------------
__global__ __launch_bounds__(256) void gemm_bn_relu_k(
    const u16* __restrict__ A, const u16* __restrict__ Bt, u16* __restrict__ C,
    int M, int N, int K,
    const float* __restrict__ bias, const float* __restrict__ g, const float* __restrict__ bb)
{
    __shared__ u16 la[64 * 40];
    __shared__ u16 lb[64 * 40];
    const int tid = threadIdx.x;
    const int lane = tid & 63, wave = tid >> 6;
    const int quad = lane >> 4, l16 = lane & 15;
    const int m0 = blockIdx.y * 64, n0 = blockIdx.x * 64;
    const f32x4 fzero = {0.f, 0.f, 0.f, 0.f};
    f32x4 acc[4];
    #pragma unroll
    for (int t = 0; t < 4; ++t) acc[t] = fzero;
    const int r = tid >> 2, cc = (tid & 3) * 8;
    for (int k0 = 0; k0 < K; k0 += 32) {
        __syncthreads();
        *(int4*)&la[r * 40 + cc] = *(const int4*)&A[(size_t)(m0 + r) * K + k0 + cc];
        *(int4*)&lb[r * 40 + cc] = *(const int4*)&Bt[(size_t)(n0 + r) * K + k0 + cc];
        __syncthreads();
        bf16x8 af = *(const bf16x8*)&la[(wave * 16 + l16) * 40 + quad * 8];
        #pragma unroll
        for (int t = 0; t < 4; ++t) {
            bf16x8 bfm = *(const bf16x8*)&lb[(t * 16 + l16) * 40 + quad * 8];
            acc[t] = __builtin_amdgcn_mfma_f32_16x16x32_bf16(af, bfm, acc[t], 0, 0, 0);
        }
    }
    const float rs = rsqrtf(1.f + 1e-5f);
    #pragma unroll
    for (int t = 0; t < 4; ++t) {
        int n = n0 + t * 16 + l16;
        float bi = bias[n];
        float sc = g[n] * rs;
        float b2 = bb[n];
        #pragma unroll
        for (int rr = 0; rr < 4; ++rr) {
            int m = m0 + wave * 16 + quad * 4 + rr;
            float v = (acc[t][rr] + bi) * sc + b2;
            v = fmaxf(v, 0.f);
            C[(size_t)m * N + n] = f2bf(v);
        }
    }
}

// ---------------- CIN layer (barrier-free n-loop, B via LDS, 256-thr blocks) ----------------
// Out[j,f] = sum_n x0[j,n] * sum_c W[f,c,n]*Xj[j,c]
// Block: 256 thr = 4 waves; tile 64 j x 128 f. Wave w: f-range w*32, all 64 j.
// Xj tile staged to LDS once (re-read per n; compiler hoists what fits in regs).
// A (W_n frags) global->reg double-buffered. One barrier total before the n-loop.
#define LOADA(buf, n_) do { \
    const u16* _p = awp + (size_t)(n_) * WSTRIDE; \
    _Pragma("unroll") for (int ms = 0; ms < 2; ++ms) \
    _Pragma("unroll") for (int kc = 0; kc < NCH; ++kc) \
        buf[ms][kc] = *(const bf16x8*)(_p + ms * 16 * CPAD + kc * 32); \
} while (0)

#define COMPUTE(A, n_) do { \
    _Pragma("unroll") for (int js = 0; js < 4; ++js) { \
        int jr = js * 16 + l16; \
        f32x4 s0 = fzero, s1 = fzero; \
        _Pragma("unroll") for (int kc = 0; kc < NCH; ++kc) { \
            bf16x8 bfr = *(const bf16x8*)&lxj[jr * LDB + kc * 32 + quad * 8]; \
            s0 = __builtin_amdgcn_mfma_f32_16x16x32_bf16(A[0][kc], bfr, s0, 0, 0, 0); \
            s1 = __builtin_amdgcn_mfma_f32_16x16x32_bf16(A[1][kc], bfr, s1, 0, 0, 0); \
        } \
        float xv = bf2f(lx0[jr * 72 + (n_)]); \
        acc[js][0] += xv * s0; \
        acc[js][1] += xv * s1; \
    } \
} while (0)

template <int CPAD>
__global__ __launch_bounds__(256, 3) void cin_layer_k(
    const u16* __restrict__ Xj, const u16* __restrict__ X0w,
    const u16* __restrict__ Wr, u16* __restrict__ Out)
{
    constexpr int NCH = CPAD / 32;
    constexpr int LDB = CPAD + 8;              // lds_xj row stride (u16)
    constexpr size_t WSTRIDE = (size_t)128 * CPAD;
    __shared__ u16 lxj[64 * LDB];
    __shared__ u16 lx0[64 * 72];
    const int tid = threadIdx.x;
    const int lane = tid & 63, wave = tid >> 6;   // wave = f-group 0..3
    const int quad = lane >> 4, l16 = lane & 15;
    const size_t j0 = (size_t)blockIdx.x * 64;
    const f32x4 fzero = {0.f, 0.f, 0.f, 0.f};

    // stage Xj tile [64][CPAD] (coalesced int4)
    constexpr int CHR = CPAD / 8;
    for (int ch = tid; ch < 64 * CHR; ch += 256) {
        int r = ch / CHR, c = (ch % CHR) * 8;
        *(int4*)&lxj[r * LDB + c] = *(const int4*)&Xj[(j0 + r) * CPAD + c];
    }
    // stage x0 scales [64][64] at stride 72
    for (int ch = tid; ch < 64 * 8; ch += 256) {
        int r = ch >> 3, c = (ch & 7) * 8;
        *(int4*)&lx0[r * 72 + c] = *(const int4*)&X0w[(j0 + r) * 64 + c];
    }

    // A base pointer: row f = wave*32 + l16 (+ms*16), col quad*8 (+kc*32)
    const u16* awp = Wr + (size_t)(wave * 32 + l16) * CPAD + quad * 8;

    __syncthreads();   // the only barrier before the epilogue

    f32x4 acc[4][2];
    #pragma unroll
    for (int js = 0; js < 4; ++js) { acc[js][0] = fzero; acc[js][1] = fzero; }

    bf16x8 a0[2][NCH], a1[2][NCH];
    LOADA(a0, 0);
    #pragma unroll 1
    for (int n = 0; n < NF - 1; n += 2) {
        LOADA(a1, n + 1);
        COMPUTE(a0, n);
        LOADA(a0, n + 2);
        COMPUTE(a1, n + 1);
    }
    COMPUTE(a0, NF - 1);

    // store: D col(lane&15)=j, row(quad*4+r)=f
    #pragma unroll
    for (int js = 0; js < 4; ++js) {
        size_t jrow = j0 + js * 16 + l16;
        #pragma unroll
        for (int ms = 0; ms < 2; ++ms) {
            f32x4 v = acc[js][ms];
            uint2 pk;
            pk.x = (u32)f2bf(v[0]) | ((u32)f2bf(v[1]) << 16);
            pk.y = (u32)f2bf(v[2]) | ((u32)f2bf(v[3]) << 16);
            *(uint2*)&Out[jrow * 128 + wave * 32 + ms * 16 + quad * 4] = pk;
        }
    }
}
#undef LOADA
#undef COMPUTE

// ---------------- final combine ----------------
__global__ __launch_bounds__(64) void final_k(
    const float* __restrict__ dense_x, const int* __restrict__ disc,
    const float* __restrict__ lin_emb, const float* __restrict__ dense_W,
    const float* __restrict__ dense_b, const u16* __restrict__ h3,
    const float* __restrict__ Wout, const float* __restrict__ bout,
    const u16* __restrict__ out0, const u16* __restrict__ out1, const u16* __restrict__ out2,
    const float* __restrict__ cw, const float* __restrict__ cb, float* __restrict__ out)
{
    const int b = blockIdx.x;
    const int lane = threadIdx.x;
    float t = 0.f;
    if (lane < DNS) {
        t += dense_x[b * DNS + lane] * dense_W[lane];
    } else if (lane < DNS + NS) {
        int i = lane - DNS;
        t += lin_emb[(size_t)i * VV + disc[b * NS + i]];
    }
    const u16* hr = h3 + (size_t)b * 256;
    #pragma unroll
    for (int rr = 0; rr < 4; ++rr) {
        int c = lane * 4 + rr;
        t += bf2f(hr[c]) * Wout[c];
    }
    const u16* obs[3] = {out0, out1, out2};
    #pragma unroll
    for (int L = 0; L < 3; ++L) {
        const u16* ob = obs[L] + (size_t)b * 16 * 128;
        #pragma unroll
        for (int h = 0; h < 2; ++h) {
            int f = lane + h * 64;
            float p = 0.f;
            #pragma unroll
            for (int d = 0; d < 16; ++d) p += bf2f(ob[d * 128 + f]);
            t += p * cw[L * 128 + f];
        }
    }
    #pragma unroll
    for (int off = 32; off > 0; off >>= 1) t += __shfl_down(t, off, 64);
    if (lane == 0) out[b] = t + dense_b[0] + bout[0] + cb[0];
}

// ---------------- launch ----------------
extern "C" void kernel_launch(void* const* d_in, const int* in_sizes, int n_in,
                              void* d_out, int out_size, void* d_ws, size_t ws_size,
                              hipStream_t stream) {
    const float* dense_x = (const float*)d_in[0];
    const int* disc      = (const int*)d_in[1];
    const float* lin_emb = (const float*)d_in[2];
    const float* emb_W   = (const float*)d_in[3];
    const float* dense_W = (const float*)d_in[4];
    const float* dense_b = (const float*)d_in[5];
    const float* W1  = (const float*)d_in[6];
    const float* b1  = (const float*)d_in[7];
    const float* g1  = (const float*)d_in[8];
    const float* bb1 = (const float*)d_in[9];
    const float* W2  = (const float*)d_in[10];
    const float* b2  = (const float*)d_in[11];
    const float* g2  = (const float*)d_in[12];
    const float* bb2 = (const float*)d_in[13];
    const float* W3  = (const float*)d_in[14];
    const float* b3  = (const float*)d_in[15];
    const float* g3  = (const float*)d_in[16];
    const float* bb3 = (const float*)d_in[17];
    const float* Wout = (const float*)d_in[18];
    const float* bout = (const float*)d_in[19];
    const float* dense_proj = (const float*)d_in[20];
    const float* cin_W0 = (const float*)d_in[21];
    const float* cin_W1 = (const float*)d_in[22];
    const float* cin_W2 = (const float*)d_in[23];
    const float* cin_ow = (const float*)d_in[24];
    const float* cin_ob = (const float*)d_in[25];

    u16* p = (u16*)d_ws;
    u16* x0  = p; p += (size_t)BD * 64;
    u16* h0  = p; p += (size_t)BB * DIN_PAD;
    u16* h1  = p; p += (size_t)BB * 1024;
    u16* h2  = p; p += (size_t)BB * 512;
    u16* h3  = p; p += (size_t)BB * 256;
    u16* W1t = p; p += (size_t)1024 * DIN_PAD;
    u16* W2t = p; p += (size_t)512 * 1024;
    u16* W3t = p; p += (size_t)256 * 512;
    u16* W0r = p; p += (size_t)NF * 128 * 64;
    u16* W1r = p; p += (size_t)NF * 128 * 128;
    u16* W2r = p; p += (size_t)NF * 128 * 128;
    u16* o0  = p; p += (size_t)BD * 128;
    u16* o1  = p; p += (size_t)BD * 128;
    u16* o2  = p; p += (size_t)BD * 128;

    prep_x0_k<<<BD * 64 / 256, 256, 0, stream>>>(emb_W, disc, dense_x, dense_proj, x0);
    prep_h0_k<<<BB * DIN_PAD / 256, 256, 0, stream>>>(emb_W, disc, dense_x, h0);
    transpose_pad_k<<<dim3(DIN_PAD / 64, 1024 / 64), 256, 0, stream>>>(W1, W1t, 429, 1024, DIN_PAD);
    transpose_pad_k<<<dim3(1024 / 64, 512 / 64), 256, 0, stream>>>(W2, W2t, 1024, 512, 1024);
    transpose_pad_k<<<dim3(512 / 64, 256 / 64), 256, 0, stream>>>(W3, W3t, 512, 256, 512);
    hipMemsetAsync(W0r, 0, (size_t)NF * 128 * 64 * sizeof(u16), stream);   // zero pads c in [39,64)
    cinw_k<<<(128 * 39 + 255) / 256, 256, 0, stream>>>(cin_W0, W0r, 39, 64);
    cinw_k<<<128 * 128 / 256, 256, 0, stream>>>(cin_W1, W1r, 128, 128);
    cinw_k<<<128 * 128 / 256, 256, 0, stream>>>(cin_W2, W2r, 128, 128);

    gemm_bn_relu_k<<<dim3(1024 / 64, BB / 64), 256, 0, stream>>>(h0, W1t, h1, BB, 1024, DIN_PAD, b1, g1, bb1);
    gemm_bn_relu_k<<<dim3(512 / 64, BB / 64), 256, 0, stream>>>(h1, W2t, h2, BB, 512, 1024, b2, g2, bb2);
    gemm_bn_relu_k<<<dim3(256 / 64, BB / 64), 256, 0, stream>>>(h2, W3t, h3, BB, 256, 512, b3, g3, bb3);

    cin_layer_k<64><<<BD / 64, 256, 0, stream>>>(x0, x0, W0r, o0);
    cin_layer_k<128><<<BD / 64, 256, 0, stream>>>(o0, x0, W1r, o1);
    cin_layer_k<128><<<BD / 64, 256, 0, stream>>>(o1, x0, W2r, o2);

    final_k<<<BB, 64, 0, stream>>>(dense_x, disc, lin_emb, dense_W, dense_b,
                                   h3, Wout, bout, o0, o1, o2, cin_ow, cin_ob, (float*)d_out);
}

// Round 5
// 675.947 us; speedup vs baseline: 1.3424x; 1.3424x over previous
//
#include <hip/hip_runtime.h>

typedef unsigned short u16;
typedef unsigned int u32;
typedef __attribute__((ext_vector_type(8))) short bf16x8;
typedef __attribute__((ext_vector_type(4))) float f32x4;

#define BB 4096
#define NS 26
#define DNS 13
#define DD 16
#define VV 100000
#define FF 128
#define NF 39
#define BD 65536
#define DIN_PAD 448

__device__ __forceinline__ float bf2f(u16 x) {
    union { u32 u; float f; } v; v.u = ((u32)x) << 16; return v.f;
}
__device__ __forceinline__ u16 f2bf(float f) {
    union { float f; u32 u; } v; v.f = f;
    u32 u = v.u;
    u32 r = (u + 0x7fffu + ((u >> 16) & 1u)) >> 16;
    return (u16)r;
}

// ---------------- prep kernels (f32 in -> bf16 workspace) ----------------

__global__ void prep_x0_k(const float* __restrict__ emb_W, const int* __restrict__ disc,
                          const float* __restrict__ dense_x, const float* __restrict__ dense_proj,
                          u16* __restrict__ x0) {
    int e = blockIdx.x * 256 + threadIdx.x;   // BD*64
    int c = e & 63;
    int j = e >> 6;
    int b = j >> 4, d = j & 15;
    float v = 0.f;
    if (c < NS) {
        int ix = disc[b * NS + c];
        v = emb_W[((size_t)c * VV + ix) * DD + d];
    } else if (c < NF) {
        int q = c - NS;
        v = dense_x[b * DNS + q] * dense_proj[q * DD + d];
    }
    x0[e] = f2bf(v);
}

__global__ void prep_h0_k(const float* __restrict__ emb_W, const int* __restrict__ disc,
                          const float* __restrict__ dense_x, u16* __restrict__ h0) {
    int e = blockIdx.x * 256 + threadIdx.x;   // B*448
    int col = e % DIN_PAD;
    int b = e / DIN_PAD;
    float v = 0.f;
    if (col < NS * DD) {
        int n = col >> 4, d = col & 15;
        int ix = disc[b * NS + n];
        v = emb_W[((size_t)n * VV + ix) * DD + d];
    } else if (col < NS * DD + DNS) {
        v = dense_x[b * DNS + col - NS * DD];
    }
    h0[e] = f2bf(v);
}

// tiled transpose: dst[n*Kpad + k] = src[k*Nn + n], zero-pad k in [K, Kpad)
__global__ void transpose_pad_k(const float* __restrict__ src, u16* __restrict__ dst,
                                int K, int Nn, int Kpad) {
    __shared__ u16 t[64][72];
    const int kb = blockIdx.x * 64, nb = blockIdx.y * 64;
    for (int i = threadIdx.x; i < 64 * 64; i += 256) {
        int kk = i >> 6, nn = i & 63;
        int k = kb + kk, n = nb + nn;
        float v = (k < K && n < Nn) ? src[(size_t)k * Nn + n] : 0.f;
        t[nn][kk] = f2bf(v);
    }
    __syncthreads();
    for (int i = threadIdx.x; i < 64 * 64; i += 256) {
        int nn = i >> 6, kk = i & 63;
        int n = nb + nn, k = kb + kk;
        if (n < Nn && k < Kpad) dst[(size_t)n * Kpad + k] = t[nn][kk];
    }
}

// cin weight rearrange with XOR swizzle for conflict-free LDS reads downstream:
// dst[n][f][swz(c)] = W[f,c,n], swz: 16-byte chunk' = chunk ^ (f & smask)
__global__ void cinw_k(const float* __restrict__ src, u16* __restrict__ dst,
                       int C, int Cpad, int smask) {
    __shared__ u16 tile[256][40];
    const int fc0 = blockIdx.x * 256;
    const int total = 128 * C;
    for (int i = threadIdx.x; i < 256 * NF; i += 256) {
        int e = fc0 * NF + i;
        if (e < total * NF) {
            int fcl = i / NF, n = i % NF;
            tile[fcl][n] = f2bf(src[e]);
        }
    }
    __syncthreads();
    for (int i = threadIdx.x; i < 256 * NF; i += 256) {
        int n = i >> 8, fcl = i & 255;
        int fc = fc0 + fcl;
        if (fc < total) {
            int f = fc / C, c = fc % C;
            int cs = (((c >> 3) ^ (f & smask)) << 3) | (c & 7);
            dst[(size_t)n * 128 * Cpad + f * Cpad + cs] = tile[fcl][n];
        }
    }
}

// ---------------- DNN GEMM: C = relu(bn(A@W + bias)) ----------------
__global__ __launch_bounds__(256) void gemm_bn_relu_k(
    const u16* __restrict__ A, const u16* __restrict__ Bt, u16* __restrict__ C,
    int M, int N, int K,
    const float* __restrict__ bias, const float* __restrict__ g, const float* __restrict__ bb)
{
    __shared__ u16 la[64 * 40];
    __shared__ u16 lb[64 * 40];
    const int tid = threadIdx.x;
    const int lane = tid & 63, wave = tid >> 6;
    const int quad = lane >> 4, l16 = lane & 15;
    const int m0 = blockIdx.y * 64, n0 = blockIdx.x * 64;
    const f32x4 fzero = {0.f, 0.f, 0.f, 0.f};
    f32x4 acc[4];
    #pragma unroll
    for (int t = 0; t < 4; ++t) acc[t] = fzero;
    const int r = tid >> 2, cc = (tid & 3) * 8;
    for (int k0 = 0; k0 < K; k0 += 32) {
        __syncthreads();
        *(int4*)&la[r * 40 + cc] = *(const int4*)&A[(size_t)(m0 + r) * K + k0 + cc];
        *(int4*)&lb[r * 40 + cc] = *(const int4*)&Bt[(size_t)(n0 + r) * K + k0 + cc];
        __syncthreads();
        bf16x8 af = *(const bf16x8*)&la[(wave * 16 + l16) * 40 + quad * 8];
        #pragma unroll
        for (int t = 0; t < 4; ++t) {
            bf16x8 bfm = *(const bf16x8*)&lb[(t * 16 + l16) * 40 + quad * 8];
            acc[t] = __builtin_amdgcn_mfma_f32_16x16x32_bf16(af, bfm, acc[t], 0, 0, 0);
        }
    }
    const float rs = rsqrtf(1.f + 1e-5f);
    #pragma unroll
    for (int t = 0; t < 4; ++t) {
        int n = n0 + t * 16 + l16;
        float bi = bias[n];
        float sc = g[n] * rs;
        float b2 = bb[n];
        #pragma unroll
        for (int rr = 0; rr < 4; ++rr) {
            int m = m0 + wave * 16 + quad * 4 + rr;
            float v = (acc[t][rr] + bi) * sc + b2;
            v = fmaxf(v, 0.f);
            C[(size_t)m * N + n] = f2bf(v);
        }
    }
}

// ---------------- CIN layer: LDS-shared W (dbuf, 1 barrier/n), B in regs ----------------
// Out[j,f] = sum_n x0[j,n] * sum_c W[f,c,n]*Xj[j,c]
// Block: 512 thr = 8 waves, tile 128j x 128f. Wave w: f-range (w&3)*32, j-half (w>>2)*64.
// W_n staged to LDS by global_load_lds (contiguous, swizzled layout from cinw_k).
#define PREFW(n_, b_) do { \
    const u16* gp_ = Wr + (size_t)(n_) * WBUF; \
    u16* lp_ = &bufW[(b_) * WBUF]; \
    _Pragma("unroll") for (int r_ = 0; r_ < NLOAD; ++r_) { \
        int ch_ = (tid + r_ * 512) * 8; \
        __builtin_amdgcn_global_load_lds( \
            (const __attribute__((address_space(1))) u32*)(gp_ + ch_), \
            (__attribute__((address_space(3))) u32*)(lp_ + ch_), 16, 0, 0); \
    } \
} while (0)

template <int CPAD>
__global__ __launch_bounds__(512, (CPAD == 64 ? 4 : 2)) void cin_layer_k(
    const u16* __restrict__ Xj, const u16* __restrict__ X0w,
    const u16* __restrict__ Wr, u16* __restrict__ Out)
{
    constexpr int NCH = CPAD / 32;
    constexpr int SMASK = (CPAD == 64) ? 7 : 15;
    constexpr int WBUF = 128 * CPAD;            // u16 per W_n
    constexpr int NLOAD = WBUF / 8 / 512;       // dwordx4 per thread per n
    __shared__ __align__(16) u16 bufW[2 * WBUF];
    __shared__ __align__(16) u16 lx0[128 * 72];
    const int tid = threadIdx.x;
    const int lane = tid & 63, wave = tid >> 6;
    const int quad = lane >> 4, l16 = lane & 15;
    const int fw = wave & 3, jh = wave >> 2;
    const size_t j0 = (size_t)blockIdx.x * 128;
    const f32x4 fzero = {0.f, 0.f, 0.f, 0.f};

    // stage x0 scales [128][64] at stride 72
    for (int ch = tid; ch < 128 * 8; ch += 512) {
        int r = ch >> 3, c = (ch & 7) * 8;
        *(int4*)&lx0[r * 72 + c] = *(const int4*)&X0w[(j0 + r) * 64 + c];
    }
    // B-frags: wave's 64 j rows of Xj, all K — registers for the whole n-loop
    bf16x8 bfr[4][NCH];
    #pragma unroll
    for (int js = 0; js < 4; ++js)
        #pragma unroll
        for (int kc = 0; kc < NCH; ++kc)
            bfr[js][kc] = *(const bf16x8*)&Xj[(j0 + jh * 64 + js * 16 + l16) * CPAD + kc * 32 + quad * 8];

    PREFW(0, 0);   // W_0 -> buf0

    f32x4 acc[4][2];
    #pragma unroll
    for (int js = 0; js < 4; ++js) { acc[js][0] = fzero; acc[js][1] = fzero; }

    #pragma unroll 1
    for (int n = 0; n < NF; ++n) {
        __syncthreads();                    // waits W_n arrival (vmcnt) + frees buf[(n+1)&1]
        if (n + 1 < NF) PREFW(n + 1, (n + 1) & 1);
        const u16* wb = &bufW[(n & 1) * WBUF];
        bf16x8 afr[2][NCH];
        #pragma unroll
        for (int ms = 0; ms < 2; ++ms)
            #pragma unroll
            for (int kc = 0; kc < NCH; ++kc)
                afr[ms][kc] = *(const bf16x8*)&wb[(fw * 32 + ms * 16 + l16) * CPAD
                                                  + (((kc * 4 + quad) ^ (l16 & SMASK)) << 3)];
        #pragma unroll
        for (int js = 0; js < 4; ++js) {
            f32x4 s0 = fzero, s1 = fzero;
            #pragma unroll
            for (int kc = 0; kc < NCH; ++kc) {
                s0 = __builtin_amdgcn_mfma_f32_16x16x32_bf16(afr[0][kc], bfr[js][kc], s0, 0, 0, 0);
                s1 = __builtin_amdgcn_mfma_f32_16x16x32_bf16(afr[1][kc], bfr[js][kc], s1, 0, 0, 0);
            }
            float xv = bf2f(lx0[(jh * 64 + js * 16 + l16) * 72 + n]);
            acc[js][0] += xv * s0;
            acc[js][1] += xv * s1;
        }
    }

    // store: D col(lane&15)=j, row(quad*4+r)=f
    #pragma unroll
    for (int js = 0; js < 4; ++js) {
        size_t jrow = j0 + jh * 64 + js * 16 + l16;
        #pragma unroll
        for (int ms = 0; ms < 2; ++ms) {
            f32x4 v = acc[js][ms];
            uint2 pk;
            pk.x = (u32)f2bf(v[0]) | ((u32)f2bf(v[1]) << 16);
            pk.y = (u32)f2bf(v[2]) | ((u32)f2bf(v[3]) << 16);
            *(uint2*)&Out[jrow * 128 + fw * 32 + ms * 16 + quad * 4] = pk;
        }
    }
}
#undef PREFW

// ---------------- final combine ----------------
__global__ __launch_bounds__(64) void final_k(
    const float* __restrict__ dense_x, const int* __restrict__ disc,
    const float* __restrict__ lin_emb, const float* __restrict__ dense_W,
    const float* __restrict__ dense_b, const u16* __restrict__ h3,
    const float* __restrict__ Wout, const float* __restrict__ bout,
    const u16* __restrict__ out0, const u16* __restrict__ out1, const u16* __restrict__ out2,
    const float* __restrict__ cw, const float* __restrict__ cb, float* __restrict__ out)
{
    const int b = blockIdx.x;
    const int lane = threadIdx.x;
    float t = 0.f;
    if (lane < DNS) {
        t += dense_x[b * DNS + lane] * dense_W[lane];
    } else if (lane < DNS + NS) {
        int i = lane - DNS;
        t += lin_emb[(size_t)i * VV + disc[b * NS + i]];
    }
    const u16* hr = h3 + (size_t)b * 256;
    #pragma unroll
    for (int rr = 0; rr < 4; ++rr) {
        int c = lane * 4 + rr;
        t += bf2f(hr[c]) * Wout[c];
    }
    const u16* obs[3] = {out0, out1, out2};
    #pragma unroll
    for (int L = 0; L < 3; ++L) {
        const u16* ob = obs[L] + (size_t)b * 16 * 128;
        #pragma unroll
        for (int h = 0; h < 2; ++h) {
            int f = lane + h * 64;
            float p = 0.f;
            #pragma unroll
            for (int d = 0; d < 16; ++d) p += bf2f(ob[d * 128 + f]);
            t += p * cw[L * 128 + f];
        }
    }
    #pragma unroll
    for (int off = 32; off > 0; off >>= 1) t += __shfl_down(t, off, 64);
    if (lane == 0) out[b] = t + dense_b[0] + bout[0] + cb[0];
}

// ---------------- launch ----------------
extern "C" void kernel_launch(void* const* d_in, const int* in_sizes, int n_in,
                              void* d_out, int out_size, void* d_ws, size_t ws_size,
                              hipStream_t stream) {
    const float* dense_x = (const float*)d_in[0];
    const int* disc      = (const int*)d_in[1];
    const float* lin_emb = (const float*)d_in[2];
    const float* emb_W   = (const float*)d_in[3];
    const float* dense_W = (const float*)d_in[4];
    const float* dense_b = (const float*)d_in[5];
    const float* W1  = (const float*)d_in[6];
    const float* b1  = (const float*)d_in[7];
    const float* g1  = (const float*)d_in[8];
    const float* bb1 = (const float*)d_in[9];
    const float* W2  = (const float*)d_in[10];
    const float* b2  = (const float*)d_in[11];
    const float* g2  = (const float*)d_in[12];
    const float* bb2 = (const float*)d_in[13];
    const float* W3  = (const float*)d_in[14];
    const float* b3  = (const float*)d_in[15];
    const float* g3  = (const float*)d_in[16];
    const float* bb3 = (const float*)d_in[17];
    const float* Wout = (const float*)d_in[18];
    const float* bout = (const float*)d_in[19];
    const float* dense_proj = (const float*)d_in[20];
    const float* cin_W0 = (const float*)d_in[21];
    const float* cin_W1 = (const float*)d_in[22];
    const float* cin_W2 = (const float*)d_in[23];
    const float* cin_ow = (const float*)d_in[24];
    const float* cin_ob = (const float*)d_in[25];

    u16* p = (u16*)d_ws;
    u16* x0  = p; p += (size_t)BD * 64;
    u16* h0  = p; p += (size_t)BB * DIN_PAD;
    u16* h1  = p; p += (size_t)BB * 1024;
    u16* h2  = p; p += (size_t)BB * 512;
    u16* h3  = p; p += (size_t)BB * 256;
    u16* W1t = p; p += (size_t)1024 * DIN_PAD;
    u16* W2t = p; p += (size_t)512 * 1024;
    u16* W3t = p; p += (size_t)256 * 512;
    u16* W0r = p; p += (size_t)NF * 128 * 64;
    u16* W1r = p; p += (size_t)NF * 128 * 128;
    u16* W2r = p; p += (size_t)NF * 128 * 128;
    u16* o0  = p; p += (size_t)BD * 128;
    u16* o1  = p; p += (size_t)BD * 128;
    u16* o2  = p; p += (size_t)BD * 128;

    prep_x0_k<<<BD * 64 / 256, 256, 0, stream>>>(emb_W, disc, dense_x, dense_proj, x0);
    prep_h0_k<<<BB * DIN_PAD / 256, 256, 0, stream>>>(emb_W, disc, dense_x, h0);
    transpose_pad_k<<<dim3(DIN_PAD / 64, 1024 / 64), 256, 0, stream>>>(W1, W1t, 429, 1024, DIN_PAD);
    transpose_pad_k<<<dim3(1024 / 64, 512 / 64), 256, 0, stream>>>(W2, W2t, 1024, 512, 1024);
    transpose_pad_k<<<dim3(512 / 64, 256 / 64), 256, 0, stream>>>(W3, W3t, 512, 256, 512);
    hipMemsetAsync(W0r, 0, (size_t)NF * 128 * 64 * sizeof(u16), stream);   // zero pads c in [39,64)
    cinw_k<<<(128 * 39 + 255) / 256, 256, 0, stream>>>(cin_W0, W0r, 39, 64, 7);
    cinw_k<<<128 * 128 / 256, 256, 0, stream>>>(cin_W1, W1r, 128, 128, 15);
    cinw_k<<<128 * 128 / 256, 256, 0, stream>>>(cin_W2, W2r, 128, 128, 15);

    gemm_bn_relu_k<<<dim3(1024 / 64, BB / 64), 256, 0, stream>>>(h0, W1t, h1, BB, 1024, DIN_PAD, b1, g1, bb1);
    gemm_bn_relu_k<<<dim3(512 / 64, BB / 64), 256, 0, stream>>>(h1, W2t, h2, BB, 512, 1024, b2, g2, bb2);
    gemm_bn_relu_k<<<dim3(256 / 64, BB / 64), 256, 0, stream>>>(h2, W3t, h3, BB, 256, 512, b3, g3, bb3);

    cin_layer_k<64><<<BD / 128, 512, 0, stream>>>(x0, x0, W0r, o0);
    cin_layer_k<128><<<BD / 128, 512, 0, stream>>>(o0, x0, W1r, o1);
    cin_layer_k<128><<<BD / 128, 512, 0, stream>>>(o1, x0, W2r, o2);

    final_k<<<BB, 64, 0, stream>>>(dense_x, disc, lin_emb, dense_W, dense_b,
                                   h3, Wout, bout, o0, o1, o2, cin_ow, cin_ob, (float*)d_out);
}